// Round 1
// baseline (321.937 us; speedup 1.0000x reference)
//
#include <hip/hip_runtime.h>

#define SPS    16
#define NS     8192            // symbols per batch row
#define NBITS  16384           // bits per batch row
#define UPLEN  (NS * SPS)      // 131072
#define KTAPS  128
#define QPB    256             // symbols (q values) handled per block

// One thread per (b, q): computes out[b, 16q .. 16q+15, 0:2] = 32 floats.
// Each output sample t=16q+p is sum over 8 taps: j = 71 - p + 16m,
//   p in [0,8):  tap rrc[16i+7-p],  symbol k = q + i - 4   (i = 0..7)
//   p in [8,16): tap rrc[16i+23-p], symbol k = q + i - 3
// Scale 4/sqrt(2) (conv * sqrt(sps) and the 1/sqrt2 Gray map) folded into
// the LDS-staged symbol values.
__global__ __launch_bounds__(256)
void qpsk_mod_kernel(const int* __restrict__ bits,
                     const float* __restrict__ rrc,
                     float* __restrict__ out) {
    __shared__ float s_taps[KTAPS];
    __shared__ float s_re[QPB + 9];   // symbols q0-4 .. q0+QPB+4
    __shared__ float s_im[QPB + 9];

    const int tid = threadIdx.x;
    const int b   = blockIdx.x >> 5;           // 32 blocks per batch row
    const int q0  = (blockIdx.x & 31) * QPB;

    if (tid < KTAPS) s_taps[tid] = rrc[tid];

    const float scale = 2.82842712474619f;     // 4 / sqrt(2)
    for (int ls = tid; ls < QPB + 9; ls += 256) {
        int s = q0 - 4 + ls;                   // global symbol index
        float re = 0.f, im = 0.f;
        if (s >= 0 && s < NS) {
            int b0 = bits[b * NBITS + 2 * s];
            int b1 = bits[b * NBITS + 2 * s + 1];
            re = (float)(1 - 2 * b1) * scale;
            im = (float)(1 - 2 * b0) * scale;
        }
        s_re[ls] = re;
        s_im[ls] = im;
    }
    __syncthreads();

    const int loc = tid;                       // q = q0 + loc
    float acc_re[16], acc_im[16];
#pragma unroll
    for (int p = 0; p < 16; ++p) { acc_re[p] = 0.f; acc_im[p] = 0.f; }

#pragma unroll
    for (int i = 0; i < 8; ++i) {
        // taps rrc[16i .. 16i+15] — wave-uniform LDS reads (broadcast)
        float tt[16];
#pragma unroll
        for (int j = 0; j < 4; ++j) {
            float4 v = *(const float4*)(&s_taps[16 * i + 4 * j]);
            tt[4 * j + 0] = v.x; tt[4 * j + 1] = v.y;
            tt[4 * j + 2] = v.z; tt[4 * j + 3] = v.w;
        }
        // symbols: k = q+i-4 -> ls = loc+i ; k = q+i-3 -> ls = loc+i+1
        float sa_re = s_re[loc + i];
        float sa_im = s_im[loc + i];
        float sb_re = s_re[loc + i + 1];
        float sb_im = s_im[loc + i + 1];
#pragma unroll
        for (int p = 0; p < 8; ++p) {
            float t = tt[7 - p];
            acc_re[p] += t * sa_re;
            acc_im[p] += t * sa_im;
        }
#pragma unroll
        for (int p = 8; p < 16; ++p) {
            float t = tt[23 - p];
            acc_re[p] += t * sb_re;
            acc_im[p] += t * sb_im;
        }
    }

    // out[b][t][c], t = 16q+p, c in {0,1} -> 32 contiguous floats per thread
    float* outp = out + (size_t)b * (UPLEN * 2) + (size_t)(q0 + loc) * 32;
#pragma unroll
    for (int p = 0; p < 16; p += 2) {
        float4 v = make_float4(acc_re[p], acc_im[p], acc_re[p + 1], acc_im[p + 1]);
        *(float4*)(outp + 2 * p) = v;
    }
}

extern "C" void kernel_launch(void* const* d_in, const int* in_sizes, int n_in,
                              void* d_out, int out_size, void* d_ws, size_t ws_size,
                              hipStream_t stream) {
    const int*   bits = (const int*)d_in[0];
    const float* rrc  = (const float*)d_in[1];
    float*       out  = (float*)d_out;

    const int B = in_sizes[0] / NBITS;         // 256
    dim3 grid(B * (NS / QPB));                 // 256 * 32 = 8192 blocks
    qpsk_mod_kernel<<<grid, 256, 0, stream>>>(bits, rrc, out);
}

// Round 2
// 316.683 us; speedup vs baseline: 1.0166x; 1.0166x over previous
//
#include <hip/hip_runtime.h>

#define SPS    16
#define NS     8192            // symbols per batch row
#define NBITS  16384           // bits per batch row
#define UPLEN  (NS * SPS)      // 131072
#define KTAPS  128
#define QPB    256             // symbols (q values) handled per block
#define SWIN   264             // QPB + 8 halo

// Thread (g = tid>>3, k = tid&7) computes phases (2k, 2k+1) of q = q0+8g+r,
// r = 0..7. Output float4 per (q,k): (re[2k], im[2k], re[2k+1], im[2k+1]) at
// float offset 32q + 4k -> lanes k=0..7 cover 128 contiguous bytes (full
// sectors per store instruction).
//
// Sample t=16q+p needs taps rrc[16i + 7-p] (p<8, symbol q+i-4) or
// rrc[16i + 23-p] (p>=8, symbol q+i-3), i=0..7. For the fixed phase pair:
//   off = k<4 ? 6-2k : 22-2k;  tap_hi = rrc[16i+off+1] -> phase 2k,
//                              tap_lo = rrc[16i+off]   -> phase 2k+1
//   sel = k<4 ? 0 : 1 (symbol shift), resolved once via cndmask so all
//   register indices stay compile-time constant.
__global__ __launch_bounds__(256)
void qpsk_mod_kernel(const int* __restrict__ bits,
                     const float* __restrict__ rrc,
                     float* __restrict__ out) {
    __shared__ float s_taps[KTAPS];
    __shared__ float s_re[SWIN];
    __shared__ float s_im[SWIN];

    const int tid = threadIdx.x;
    const int b   = blockIdx.x >> 5;           // 32 blocks per batch row
    const int q0  = (blockIdx.x & 31) * QPB;

    if (tid < KTAPS) s_taps[tid] = rrc[tid];

    const float scale = 2.82842712474619f;     // 4 / sqrt(2)
    for (int ls = tid; ls < SWIN; ls += 256) {
        int s = q0 - 4 + ls;                   // global symbol index
        float re = 0.f, im = 0.f;
        if (s >= 0 && s < NS) {
            int2 bb = *(const int2*)(bits + b * NBITS + 2 * s);
            re = (float)(1 - 2 * bb.y) * scale;
            im = (float)(1 - 2 * bb.x) * scale;
        }
        s_re[ls] = re;
        s_im[ls] = im;
    }
    __syncthreads();

    const int k = tid & 7;
    const int g = tid >> 3;
    const int off = (k < 4) ? (6 - 2 * k) : (22 - 2 * k);
    const bool hi_half = (k >= 4);             // sel = 1

    // taps: one pair per tap-group, hoisted (8 x ds_read_b64)
    float tlo[8], thi[8];
#pragma unroll
    for (int i = 0; i < 8; ++i) {
        float2 tp = *(const float2*)(&s_taps[16 * i + off]);
        tlo[i] = tp.x;                         // -> phase 2k+1
        thi[i] = tp.y;                         // -> phase 2k
    }

    // symbol window: 16 floats per channel, aligned b128 reads, then apply
    // the sel shift with cndmask (static indices thereafter)
    float wre[16], wim[16];
#pragma unroll
    for (int j = 0; j < 16; j += 4) {
        float4 vr = *(const float4*)(&s_re[g * 8 + j]);
        wre[j] = vr.x; wre[j + 1] = vr.y; wre[j + 2] = vr.z; wre[j + 3] = vr.w;
        float4 vi = *(const float4*)(&s_im[g * 8 + j]);
        wim[j] = vi.x; wim[j + 1] = vi.y; wim[j + 2] = vi.z; wim[j + 3] = vi.w;
    }
    float sre[15], sim[15];
#pragma unroll
    for (int j = 0; j < 15; ++j) {
        sre[j] = hi_half ? wre[j + 1] : wre[j];
        sim[j] = hi_half ? wim[j + 1] : wim[j];
    }

    float* outp = out + (size_t)b * (UPLEN * 2)
                      + (size_t)(q0 + g * 8) * 32 + 4 * k;
#pragma unroll
    for (int r = 0; r < 8; ++r) {
        float a0 = 0.f, a1 = 0.f, a2 = 0.f, a3 = 0.f;
#pragma unroll
        for (int i = 0; i < 8; ++i) {
            float sr = sre[r + i];
            float si = sim[r + i];
            a0 += thi[i] * sr;                 // re, phase 2k
            a1 += thi[i] * si;                 // im, phase 2k
            a2 += tlo[i] * sr;                 // re, phase 2k+1
            a3 += tlo[i] * si;                 // im, phase 2k+1
        }
        *(float4*)(outp + 32 * r) = make_float4(a0, a1, a2, a3);
    }
}

extern "C" void kernel_launch(void* const* d_in, const int* in_sizes, int n_in,
                              void* d_out, int out_size, void* d_ws, size_t ws_size,
                              hipStream_t stream) {
    const int*   bits = (const int*)d_in[0];
    const float* rrc  = (const float*)d_in[1];
    float*       out  = (float*)d_out;

    const int B = in_sizes[0] / NBITS;         // 256
    dim3 grid(B * (NS / QPB));                 // 8192 blocks
    qpsk_mod_kernel<<<grid, 256, 0, stream>>>(bits, rrc, out);
}

// Round 4
// 278.933 us; speedup vs baseline: 1.1542x; 1.1353x over previous
//
#include <hip/hip_runtime.h>

#define SPS    16
#define NS     8192            // symbols per batch row
#define NBITS  16384           // bits per batch row
#define UPLEN  (NS * SPS)      // 131072
#define KTAPS  128
#define QPB    256             // symbols (q values) handled per block
#define SWIN   264             // QPB + 8 halo

typedef float vfloat4 __attribute__((ext_vector_type(4)));

// Thread (g = tid>>3, k = tid&7) computes phases (2k, 2k+1) of q = q0+8g+r,
// r = 0..7. Output vfloat4 per (q,k): (re[2k], im[2k], re[2k+1], im[2k+1]) at
// float offset 32q + 4k -> lanes k=0..7 cover 128 contiguous bytes per store.
//
// Sample t=16q+p needs taps rrc[16i + 7-p] (p<8, symbol q+i-4) or
// rrc[16i + 23-p] (p>=8, symbol q+i-3), i=0..7. For the fixed phase pair:
//   off = k<4 ? 6-2k : 22-2k;  tap rrc[16i+off+1] -> phase 2k,
//                              tap rrc[16i+off]   -> phase 2k+1
// The p>=8 symbol shift is folded into the LDS window base address
// (base = g*8 + (k>=4)), so no register-level select is needed.
__global__ __launch_bounds__(256, 4)
void qpsk_mod_kernel(const int* __restrict__ bits,
                     const float* __restrict__ rrc,
                     float* __restrict__ out) {
    __shared__ float s_taps[KTAPS];
    __shared__ float s_re[SWIN];
    __shared__ float s_im[SWIN];

    const int tid = threadIdx.x;
    const int b   = blockIdx.x >> 5;           // 32 blocks per batch row
    const int q0  = (blockIdx.x & 31) * QPB;

    if (tid < KTAPS) s_taps[tid] = rrc[tid];

    const float scale = 2.82842712474619f;     // 4 / sqrt(2): sqrt(sps)/sqrt(2)
    for (int ls = tid; ls < SWIN; ls += 256) {
        int s = q0 - 4 + ls;                   // global symbol index
        float re = 0.f, im = 0.f;
        if (s >= 0 && s < NS) {
            int2 bb = *(const int2*)(bits + b * NBITS + 2 * s);
            re = (float)(1 - 2 * bb.y) * scale;
            im = (float)(1 - 2 * bb.x) * scale;
        }
        s_re[ls] = re;
        s_im[ls] = im;
    }
    __syncthreads();

    const int k    = tid & 7;
    const int g    = tid >> 3;
    const int off  = (k < 4) ? (6 - 2 * k) : (22 - 2 * k);
    const int base = g * 8 + (k >= 4 ? 1 : 0);

    // taps: one pair per tap-group (8 x ds_read_b64, wave-broadcast friendly)
    float tlo[8], thi[8];
#pragma unroll
    for (int i = 0; i < 8; ++i) {
        float2 tp = *(const float2*)(&s_taps[16 * i + off]);
        tlo[i] = tp.x;                         // -> phase 2k+1
        thi[i] = tp.y;                         // -> phase 2k
    }

    // 15-symbol window, sel folded into base (scalar LDS reads, 2-way banks)
    float sre[15], sim[15];
#pragma unroll
    for (int j = 0; j < 15; ++j) {
        sre[j] = s_re[base + j];
        sim[j] = s_im[base + j];
    }

    float* outp = out + (size_t)b * (UPLEN * 2)
                      + (size_t)(q0 + g * 8) * 32 + 4 * k;
#pragma unroll
    for (int r = 0; r < 8; ++r) {
        float a0 = 0.f, a1 = 0.f, a2 = 0.f, a3 = 0.f;
#pragma unroll
        for (int i = 0; i < 8; ++i) {
            float sr = sre[r + i];
            float si = sim[r + i];
            a0 += thi[i] * sr;                 // re, phase 2k
            a1 += thi[i] * si;                 // im, phase 2k
            a2 += tlo[i] * sr;                 // re, phase 2k+1
            a3 += tlo[i] * si;                 // im, phase 2k+1
        }
        vfloat4 v = {a0, a1, a2, a3};
        __builtin_nontemporal_store(v, (vfloat4*)(outp + 32 * r));
    }
}

extern "C" void kernel_launch(void* const* d_in, const int* in_sizes, int n_in,
                              void* d_out, int out_size, void* d_ws, size_t ws_size,
                              hipStream_t stream) {
    const int*   bits = (const int*)d_in[0];
    const float* rrc  = (const float*)d_in[1];
    float*       out  = (float*)d_out;

    const int B = in_sizes[0] / NBITS;         // 256
    dim3 grid(B * (NS / QPB));                 // 8192 blocks
    qpsk_mod_kernel<<<grid, 256, 0, stream>>>(bits, rrc, out);
}